// Round 12
// baseline (428.995 us; speedup 1.0000x reference)
//
#include <hip/hip_runtime.h>

// MaskTypeProbabilitiesLayer R12: all-grid-stride, barrier-free, 3 kernels.
//   gt = in[b,t,0]; base = TYPE_TABLE[gt]; gt in {4,5,6} -> dynamic mask from
//   first-occurrence index of 5 / 6 vs idx = min(t+1, 2047).
// Bit-packed: TYPE_TABLE[0]=0x02 [1]=0x06 [2]=0x10 [3]=0xF8 [7]=0x80;
//   NO_TIMESIGN=0x20 NO_TEMPO=0x40 FULL=0xF8.
//
// R11 post-mortem: per-thread MLP was never the limiter (one wave int4 load
// = 8 lines in flight; 16 waves/CU x 8 = plenty). Monolithic phase-locked
// block-per-row structure runs 3.2 TB/s combined vs 6.8 TB/s fill regime.
// R12 copies the proven-fast regime: 256-thr blocks, huge grid-stride, no
// __syncthreads anywhere; cross-position state via sparse global atomicMin.

#define SEQ_L 2048
#define NF 11
#define BATCH 1024
#define IN_CHUNKS (BATCH * SEQ_L * NF / 4)   // 5,767,168 int4
#define ROW_CHUNKS (SEQ_L * NF / 4)          // 5632 (64-aligned per wave)
#define OUT_CHUNKS (BATCH * SEQ_L * 8 / 4)   // 4,194,304 int4
#define K1_GRID 2816                         // x256thr x8 passes = IN_CHUNKS
#define K1_PASSES 8
#define K2_GRID 4096                         // x256thr x4 passes = OUT_CHUNKS
#define K2_PASSES 4

// ---- K0: init first5/first6 (2*1024 u32) to +inf ----
__global__ __launch_bounds__(256)
void mask_init_kernel(unsigned* __restrict__ firsts) {
    const int i = blockIdx.x * 256 + threadIdx.x;
    if (i < 2 * BATCH) firsts[i] = 0xFFFFFFFFu;
}

// ---- K1: stream input, extract gt, sparse atomicMin of first 5/6 ----
__global__ __launch_bounds__(256)
void mask_scan_kernel(const int* __restrict__ in, int* __restrict__ gt_out,
                      unsigned* __restrict__ first5, unsigned* __restrict__ first6) {
    const int base = blockIdx.x * 256 + threadIdx.x;
    const int stride = K1_GRID * 256;
    const int4* inv = (const int4*)in;
    #pragma unroll
    for (int p = 0; p < K1_PASSES; ++p) {
        const int c = base + p * stride;           // 0..IN_CHUNKS-1, lane-dense
        const int4 v = inv[c];
        const int row = c / ROW_CHUNKS;            // wave-uniform (5632 % 64 == 0)
        const int jr  = (c - row * ROW_CHUNKS) * 4;  // int index within row
        const int mi  = (jr + 10) / 11;            // at most one multiple of 11 in [jr,jr+4)
        const int pos = mi * 11 - jr;              // 0..10
        if (pos < 4) {
            const int gv = (pos == 0) ? v.x : (pos == 1) ? v.y
                         : (pos == 2) ? v.z : v.w;
            gt_out[row * SEQ_L + mi] = gv;
            if (gv == 5) atomicMin(&first5[row], (unsigned)mi);
            if (gv == 6) atomicMin(&first6[row], (unsigned)mi);
        }
    }
}

// ---- K2: fill-style dense emit of the 66 MB mask ----
__global__ __launch_bounds__(256)
void mask_emit_kernel(const int* __restrict__ gt, const unsigned* __restrict__ first5,
                      const unsigned* __restrict__ first6, int* __restrict__ out) {
    const int base = blockIdx.x * 256 + threadIdx.x;
    const int stride = K2_GRID * 256;
    const unsigned long long pack = 0x80000000F8100602ULL;
    int4* outv = (int4*)out;
    #pragma unroll
    for (int p = 0; p < K2_PASSES; ++p) {
        const int c   = base + p * stride;     // 0..OUT_CHUNKS-1, lane-dense
        const int tg  = c >> 1;                // global position index
        const int half = c & 1;
        const int row = tg >> 11;              // wave-uniform (8192 chunks/row)
        const int t   = tg & (SEQ_L - 1);
        const int gv  = gt[tg];                // pairs of lanes share a dword
        unsigned m;
        if (gv >= 4 && gv <= 6) {
            const unsigned idx = (unsigned)((t + 1 < SEQ_L - 1) ? (t + 1) : (SEQ_L - 1));
            m = (first5[row] > idx) ? 0x20u : ((first6[row] > idx) ? 0x40u : 0xF8u);
        } else {
            const int gc = gv < 0 ? 0 : (gv > 8 ? 8 : gv);
            m = (gc >= 8) ? 0u : (unsigned)((pack >> (gc * 8)) & 0xFFu);
        }
        const unsigned nib = half ? (m >> 4) : m;
        int4 w;
        w.x = (int)((nib >> 0) & 1u);
        w.y = (int)((nib >> 1) & 1u);
        w.z = (int)((nib >> 2) & 1u);
        w.w = (int)((nib >> 3) & 1u);
        outv[c] = w;
    }
}

extern "C" void kernel_launch(void* const* d_in, const int* in_sizes, int n_in,
                              void* d_out, int out_size, void* d_ws, size_t ws_size,
                              hipStream_t stream) {
    const int* in = (const int*)d_in[0];
    int* out = (int*)d_out;

    // ws layout: [first5: 1024 u32][first6: 1024 u32][gt: 1024*2048 i32]
    unsigned* firsts = (unsigned*)d_ws;
    unsigned* first5 = firsts;
    unsigned* first6 = firsts + BATCH;
    int* gt = (int*)(firsts + 2 * BATCH);

    mask_init_kernel<<<(2 * BATCH + 255) / 256, 256, 0, stream>>>(firsts);
    mask_scan_kernel<<<K1_GRID, 256, 0, stream>>>(in, gt, first5, first6);
    mask_emit_kernel<<<K2_GRID, 256, 0, stream>>>(gt, first5, first6, out);
}

// Round 14
// 155.645 us; speedup vs baseline: 2.7562x; 2.7562x over previous
//
#include <hip/hip_runtime.h>

// MaskTypeProbabilitiesLayer R14: R11 monolithic structure + NONTEMPORAL input
// loads (single-variable experiment on the cache-allocation path).
// R13 failed to compile: __builtin_nontemporal_load rejects HIP_vector_type*;
// use a native clang ext_vector_type(4) int alias instead (same dwordx4 load).
//
//   gt = in[b,t,0]; base = TYPE_TABLE[gt]; gt in {4,5,6} -> dynamic mask from
//   first-occurrence index of 5 / 6 vs idx = min(t+1, 2047).
// Bit-packed: TYPE_TABLE[0]=0x02 [1]=0x06 [2]=0x10 [3]=0xF8 [7]=0x80;
//   NO_TIMESIGN=0x20 NO_TEMPO=0x40 FULL=0xF8.
//
// Ledger: R6 gather 55us | R7 +occ 56 | R8 dense 59 | R9 dense-stores ~50 |
// R10 split neutral | R11 sched_barrier neutral | R12 global-atomics 340us(!).
// Facts: read stream pinned 2.0-2.4 TB/s in 5 configs; writes 6.8 TB/s;
// per-thread MLP irrelevant; global atomics forbidden. Testing: LLC/L2
// allocation path on the harness-restored (dirty) input -> nt loads bypass.

#define SEQ_L 2048
#define NF 11
#define BLOCK 512
#define PASSES 11                    // 5632 int4 per row / 512 threads
#define OPASS 8                      // 4096 out-int4 per row / 512 threads

typedef int nint4 __attribute__((ext_vector_type(4)));

__global__ __launch_bounds__(BLOCK)
void mask_type_prob_kernel(const int* __restrict__ in, int* __restrict__ out) {
    __shared__ int s_gt[SEQ_L];
    __shared__ unsigned s_f5, s_f6;

    const int b   = blockIdx.x;
    const int tid = threadIdx.x;

    if (tid == 0) { s_f5 = 0xFFFFFFFFu; s_f6 = 0xFFFFFFFFu; }
    __syncthreads();

    const nint4* rowv = (const nint4*)(in + (size_t)b * SEQ_L * NF);

    // ---- Phase 1: stream row with NONTEMPORAL int4 loads, extract feature 0 ----
    unsigned f5 = 0xFFFFFFFFu, f6 = 0xFFFFFFFFu;
    #pragma unroll
    for (int p = 0; p < PASSES; ++p) {
        const int i4 = tid + p * BLOCK;   // 0..5631, lane-dense
        const nint4 v = __builtin_nontemporal_load(&rowv[i4]);
        const int j  = i4 * 4;            // int index of v[0]
        const int mi  = (j + 10) / 11;    // at most one multiple of 11 in [j,j+4)
        const int pos = mi * 11 - j;      // 0..10
        if (pos < 4) {
            const int gv = v[pos & 3];
            s_gt[mi] = gv;
            if (gv == 5) f5 = min(f5, (unsigned)mi);
            if (gv == 6) f6 = min(f6, (unsigned)mi);
        }
    }

    // Wave min-reduce, one LDS atomic per wave (R12 taught: NEVER global).
    #pragma unroll
    for (int off = 32; off >= 1; off >>= 1) {
        f5 = min(f5, (unsigned)__shfl_xor((int)f5, off, 64));
        f6 = min(f6, (unsigned)__shfl_xor((int)f6, off, 64));
    }
    if ((tid & 63) == 0) {
        if (f5 != 0xFFFFFFFFu) atomicMin(&s_f5, f5);
        if (f6 != 0xFFFFFFFFu) atomicMin(&s_f6, f6);
    }
    __syncthreads();

    const unsigned first5 = s_f5;
    const unsigned first6 = s_f6;

    const unsigned long long pack = 0x80000000F8100602ULL;

    // ---- Phase 2: lane-dense int4 stores (chunk c = 16B half of pos c>>1) ----
    int4* orowv = (int4*)(out + (size_t)b * SEQ_L * 8);

    #pragma unroll
    for (int k = 0; k < OPASS; ++k) {
        const int c    = tid + k * BLOCK;  // 0..4095, lanes contiguous
        const int t    = c >> 1;
        const int half = c & 1;
        const int gv   = s_gt[t];          // 2-way LDS aliasing: free
        unsigned m;
        if (gv >= 4 && gv <= 6) {
            const unsigned idx = (unsigned)((t + 1 < SEQ_L - 1) ? (t + 1) : (SEQ_L - 1));
            m = (first5 > idx) ? 0x20u : ((first6 > idx) ? 0x40u : 0xF8u);
        } else {
            const int gc = gv < 0 ? 0 : (gv > 8 ? 8 : gv);
            m = (gc >= 8) ? 0u : (unsigned)((pack >> (gc * 8)) & 0xFFu);
        }
        const unsigned nib = half ? (m >> 4) : m;
        int4 w;
        w.x = (int)((nib >> 0) & 1u);
        w.y = (int)((nib >> 1) & 1u);
        w.z = (int)((nib >> 2) & 1u);
        w.w = (int)((nib >> 3) & 1u);
        orowv[c] = w;
    }
}

extern "C" void kernel_launch(void* const* d_in, const int* in_sizes, int n_in,
                              void* d_out, int out_size, void* d_ws, size_t ws_size,
                              hipStream_t stream) {
    const int* in = (const int*)d_in[0];
    int* out = (int*)d_out;
    const int batch = in_sizes[0] / (SEQ_L * NF);   // 1024
    mask_type_prob_kernel<<<batch, BLOCK, 0, stream>>>(in, out);
}